// Round 6
// baseline (644.685 us; speedup 1.0000x reference)
//
#include <hip/hip_runtime.h>

#define N_ROWS   524288
#define W_BINS   101
#define EPS_F    1e-3f
#define RPB      64                    // rows per block (one 64x101 tile)
#define NBLK     (N_ROWS / RPB)        // 8192 blocks
#define TILE_F   (RPB * W_BINS)        // 6464 floats per tile (25,856 B LDS)
#define THREADS  256                   // 4 waves; each row split across a lane QUARTET

typedef const float __attribute__((address_space(1)))* gptr_t;
typedef float __attribute__((address_space(3)))* sptr_t;

// R2 body (best measured: 292.3 us, absmax 0) + fused last-block-done tail.
// One block = one 64-row tile, FOUR waves, flat DMA-to-LDS staging. Each row is
// computed by 4 lanes of one wave: row r = wv*16 + (tid&15), quarter h =
// (tid>>4)&3 owns cols {0..25, 26..50, 51..75, 76..100}; combine = shfl_xor
// 16/32. 25.9 KB LDS -> 6 blocks/CU, 24 waves/CU. After writing its partial,
// each block takes a ticket; the last one reduces all partials (double) and
// writes out. Graph-safe: plain launch, no spin, device-scope fences only.
__global__ __launch_bounds__(THREADS) void mrl_main(const float* __restrict__ x,
                                                    const int* __restrict__ tgt,
                                                    float4* __restrict__ partial,
                                                    unsigned* __restrict__ ticket,
                                                    float* __restrict__ out) {
    __shared__ float  sm[TILE_F];
    __shared__ float4 wsum[4];
    __shared__ int    is_last;
    const int tid = threadIdx.x;                 // 0..255
    const int wv  = tid >> 6;                    // wave 0..3
    const float* gbase = x + (size_t)blockIdx.x * TILE_F;

    // Flat async DMA: 16 B/lane. Chunk q covers floats [q*1024, +1024);
    // wave w's sub-chunk [q*1024 + w*256, +256). LDS dest base is wave-uniform.
    #pragma unroll
    for (int q = 0; q < 6; ++q) {
        __builtin_amdgcn_global_load_lds((gptr_t)(gbase + q * 1024 + tid * 4),
                                         (sptr_t)(sm + q * 1024 + (wv << 8)), 16, 0, 0);
    }
    if (tid < 80) {                              // tail: floats 6144..6463
        __builtin_amdgcn_global_load_lds((gptr_t)(gbase + 6144 + tid * 4),
                                         (sptr_t)(sm + 6144 + (wv << 8)), 16, 0, 0);
    }

    const int r = (wv << 4) | (tid & 15);        // row 0..63 (16 rows per wave)
    const int h = (tid >> 4) & 3;                // which quarter of the row
    const int t = tgt[blockIdx.x * RPB + r];     // broadcast across the quartet

    __syncthreads();                             // drains vmcnt -> tile visible

    // h==0 owns 26 cols (0..25), h>0 own 25 each. Max index r*101+100 never
    // crosses a row. Banks: (5r + {0,26,51,76}) mod 32 spreads <=4-way.
    const int cb = (h == 0) ? 0 : (h * 25 + 1);  // {0,26,51,76}
    const float* rp = sm + r * W_BINS + cb;

    // Pass 1: e_i = exp(x_i) kept in registers; accumulate se, sum(e*a), e_gt.
    float e[25];
    float e25 = 0.f;
    float se0 = 0.f, se1 = 0.f, sa0 = 0.f, sa1 = 0.f, eg = 0.f;
    #pragma unroll
    for (int i = 0; i < 24; i += 2) {
        float E0 = __expf(rp[i]);
        float E1 = __expf(rp[i + 1]);
        e[i] = E0; e[i + 1] = E1;
        se0 += E0; sa0 += E0 * (float)(cb + i);
        se1 += E1; sa1 += E1 * (float)(cb + i + 1);
        eg = (cb + i     == t) ? E0 : eg;
        eg = (cb + i + 1 == t) ? E1 : eg;
    }
    {                                            // 25th owned col (i = 24)
        float E = __expf(rp[24]);
        e[24] = E;
        se0 += E; sa0 += E * (float)(cb + 24);
        eg = (cb + 24 == t) ? E : eg;
    }
    if (h == 0) {                                // 26th col of quarter 0 (col 25)
        e25 = __expf(rp[25]);
        se1 += e25; sa1 += e25 * 25.0f;
        eg = (t == 25) ? e25 : eg;
    }
    float se  = se0 + se1;
    float sea = sa0 + sa1;

    // Combine the 4 row-partners (tid bits 4,5 = h; same wave).
    se  += __shfl_xor(se, 16);  se  += __shfl_xor(se, 32);
    sea += __shfl_xor(sea, 16); sea += __shfl_xor(sea, 32);
    eg  += __shfl_xor(eg, 16);  eg  += __shfl_xor(eg, 32);
    const float egt = eg;                        // bit-exact e[t] (+0 from partners)
    const float inv = __builtin_amdgcn_rcpf(se);

    float sq = 0.f;
    if (h == 0) {                                // count mean-loss once per row
        float d = sea * inv - (float)t;
        sq = d * d;
    }

    // Pass 2: pure-register. e-space compare is scale-invariant; i==t -> not lt.
    float rc0 = 0.f, rc1 = 0.f;
    int   k   = 0;
    #pragma unroll
    for (int i = 0; i < 24; i += 2) {
        float E0 = e[i], E1 = e[i + 1];
        bool  l0 = E0 < egt, l1 = E1 < egt;
        float q0 = (l0 ? E0 * inv : 0.f) + EPS_F;
        float q1 = (l1 ? E1 * inv : 0.f) + EPS_F;
        rc0 -= q0 * __logf(q0);
        rc1 -= q1 * __logf(q1);
        k   += (l0 ? 0 : 1) + (l1 ? 0 : 1);
    }
    {
        float E = e[24];
        bool  l = E < egt;
        float q = (l ? E * inv : 0.f) + EPS_F;
        rc0 -= q * __logf(q);
        k   += l ? 0 : 1;
    }
    if (h == 0) {
        bool  l = e25 < egt;
        float q = (l ? e25 * inv : 0.f) + EPS_F;
        rc1 -= q * __logf(q);
        k   += l ? 0 : 1;
    }
    float rc = rc0 + rc1;
    float kf = (float)k;                         // <= 101, exact in float

    // Wave butterfly over the 3 per-lane scalars (sq nonzero only at h==0).
    #pragma unroll
    for (int off = 32; off >= 1; off >>= 1) {
        sq += __shfl_xor(sq, off);
        rc += __shfl_xor(rc, off);
        kf += __shfl_xor(kf, off);
    }
    if ((tid & 63) == 0) wsum[wv] = make_float4(sq, rc, kf, 0.f);
    __syncthreads();
    if (tid == 0) {
        float4 a = wsum[0], b = wsum[1], c = wsum[2], d = wsum[3];
        partial[blockIdx.x] = make_float4(a.x + b.x + c.x + d.x,
                                          a.y + b.y + c.y + d.y,
                                          a.z + b.z + c.z + d.z, 0.f);
        __threadfence();                         // release: partial visible device-wide
        unsigned old = atomicAdd(ticket, 1u);    // device-scope by default (G12)
        is_last = (old == NBLK - 1) ? 1 : 0;
    }
    __syncthreads();

    if (is_last) {
        __threadfence();                         // acquire: see all 8192 partials
        double s = 0.0, rr = 0.0, kk = 0.0;
        #pragma unroll
        for (int i = 0; i < NBLK / THREADS; ++i) {   // 32 coalesced strided reads
            float4 v = partial[tid + i * THREADS];
            s += (double)v.x; rr += (double)v.y; kk += (double)v.z;
        }
        #pragma unroll
        for (int off = 32; off >= 1; off >>= 1) {
            s  += __shfl_xor(s, off);
            rr += __shfl_xor(rr, off);
            kk += __shfl_xor(kk, off);
        }
        __shared__ double sd[12];
        if ((tid & 63) == 0) { sd[wv * 3 + 0] = s; sd[wv * 3 + 1] = rr; sd[wv * 3 + 2] = kk; }
        __syncthreads();
        if (tid == 0) {
            double S = sd[0] + sd[3] + sd[6] + sd[9];
            double R = sd[1] + sd[4] + sd[7] + sd[10];
            double K = sd[2] + sd[5] + sd[8] + sd[11];
            const double n = (double)N_ROWS;
            out[0] = (float)(0.1  * (S / n));    // LAMBDA_1 * mean_loss (0.2 * 0.5)
            out[1] = (float)(0.05 * (R / n));    // LAMBDA_2 * residue_loss
            out[2] = (float)(K / n);             // batch_average_K
        }
    }
}

extern "C" void kernel_launch(void* const* d_in, const int* in_sizes, int n_in,
                              void* d_out, int out_size, void* d_ws, size_t ws_size,
                              hipStream_t stream) {
    const float* x   = (const float*)d_in[0];
    const int*   tgt = (const int*)d_in[1];
    float*    out     = (float*)d_out;
    float4*   partial = (float4*)d_ws;                    // 8192 * 16 B = 128 KiB
    unsigned* ticket  = (unsigned*)((char*)d_ws + NBLK * sizeof(float4));

    // Zero the ticket each iteration (workspace may be re-poisoned). Graph-safe.
    hipMemsetAsync(ticket, 0, sizeof(unsigned), stream);
    mrl_main<<<NBLK, THREADS, 0, stream>>>(x, tgt, partial, ticket, out);
}

// Round 8
// 327.921 us; speedup vs baseline: 1.9660x; 1.9660x over previous
//
#include <hip/hip_runtime.h>

#define N_ROWS   524288
#define W_BINS   101
#define EPS_F    1e-3f
#define RPB      64                    // rows per block (one 64x101 tile)
#define NBLK     (N_ROWS / RPB)        // 8192 blocks
#define TILE_F   (RPB * W_BINS)        // 6464 floats per tile (25,856 B LDS)
#define THREADS  256                   // 4 waves; each row split across a lane QUARTET

typedef const float __attribute__((address_space(1)))* gptr_t;
typedef float __attribute__((address_space(3)))* sptr_t;

// R2 body (best measured: 292.3 us, absmax 0) + fused last-block-done tail.
// R6 lesson: __threadfence() = agent fence = per-block L2 writeback/invalidate
// on gfx950 -> 8192 serialized wbl2 ops ~ 430 us. Replaced with RELAXED
// agent-scope atomics (sc1 load/store straight to the coherent point, ZERO
// cache maintenance) + a manual vmcnt(0) between partial stores and the
// ticket RMW. Ticket total order then guarantees the last block sees all
// partials via scoped loads. Control flow identical to R6 (proven correct).
__global__ __launch_bounds__(THREADS) void mrl_main(const float* __restrict__ x,
                                                    const int* __restrict__ tgt,
                                                    float4* __restrict__ partial,
                                                    unsigned* __restrict__ ticket,
                                                    float* __restrict__ out) {
    __shared__ float  sm[TILE_F];
    __shared__ float4 wsum[4];
    __shared__ int    is_last;
    const int tid = threadIdx.x;                 // 0..255
    const int wv  = tid >> 6;                    // wave 0..3
    const float* gbase = x + (size_t)blockIdx.x * TILE_F;

    // Flat async DMA: 16 B/lane. Chunk q covers floats [q*1024, +1024);
    // wave w's sub-chunk [q*1024 + w*256, +256). LDS dest base is wave-uniform.
    #pragma unroll
    for (int q = 0; q < 6; ++q) {
        __builtin_amdgcn_global_load_lds((gptr_t)(gbase + q * 1024 + tid * 4),
                                         (sptr_t)(sm + q * 1024 + (wv << 8)), 16, 0, 0);
    }
    if (tid < 80) {                              // tail: floats 6144..6463
        __builtin_amdgcn_global_load_lds((gptr_t)(gbase + 6144 + tid * 4),
                                         (sptr_t)(sm + 6144 + (wv << 8)), 16, 0, 0);
    }

    const int r = (wv << 4) | (tid & 15);        // row 0..63 (16 rows per wave)
    const int h = (tid >> 4) & 3;                // which quarter of the row
    const int t = tgt[blockIdx.x * RPB + r];     // broadcast across the quartet

    __syncthreads();                             // drains vmcnt -> tile visible

    // h==0 owns 26 cols (0..25), h>0 own 25 each. Max index r*101+100 never
    // crosses a row. Banks: (5r + {0,26,51,76}) mod 32 spreads <=4-way.
    const int cb = (h == 0) ? 0 : (h * 25 + 1);  // {0,26,51,76}
    const float* rp = sm + r * W_BINS + cb;

    // Pass 1: e_i = exp(x_i) kept in registers; accumulate se, sum(e*a), e_gt.
    float e[25];
    float e25 = 0.f;
    float se0 = 0.f, se1 = 0.f, sa0 = 0.f, sa1 = 0.f, eg = 0.f;
    #pragma unroll
    for (int i = 0; i < 24; i += 2) {
        float E0 = __expf(rp[i]);
        float E1 = __expf(rp[i + 1]);
        e[i] = E0; e[i + 1] = E1;
        se0 += E0; sa0 += E0 * (float)(cb + i);
        se1 += E1; sa1 += E1 * (float)(cb + i + 1);
        eg = (cb + i     == t) ? E0 : eg;
        eg = (cb + i + 1 == t) ? E1 : eg;
    }
    {                                            // 25th owned col (i = 24)
        float E = __expf(rp[24]);
        e[24] = E;
        se0 += E; sa0 += E * (float)(cb + 24);
        eg = (cb + 24 == t) ? E : eg;
    }
    if (h == 0) {                                // 26th col of quarter 0 (col 25)
        e25 = __expf(rp[25]);
        se1 += e25; sa1 += e25 * 25.0f;
        eg = (t == 25) ? e25 : eg;
    }
    float se  = se0 + se1;
    float sea = sa0 + sa1;

    // Combine the 4 row-partners (tid bits 4,5 = h; same wave).
    se  += __shfl_xor(se, 16);  se  += __shfl_xor(se, 32);
    sea += __shfl_xor(sea, 16); sea += __shfl_xor(sea, 32);
    eg  += __shfl_xor(eg, 16);  eg  += __shfl_xor(eg, 32);
    const float egt = eg;                        // bit-exact e[t] (+0 from partners)
    const float inv = __builtin_amdgcn_rcpf(se);

    float sq = 0.f;
    if (h == 0) {                                // count mean-loss once per row
        float d = sea * inv - (float)t;
        sq = d * d;
    }

    // Pass 2: pure-register. e-space compare is scale-invariant; i==t -> not lt.
    float rc0 = 0.f, rc1 = 0.f;
    int   k   = 0;
    #pragma unroll
    for (int i = 0; i < 24; i += 2) {
        float E0 = e[i], E1 = e[i + 1];
        bool  l0 = E0 < egt, l1 = E1 < egt;
        float q0 = (l0 ? E0 * inv : 0.f) + EPS_F;
        float q1 = (l1 ? E1 * inv : 0.f) + EPS_F;
        rc0 -= q0 * __logf(q0);
        rc1 -= q1 * __logf(q1);
        k   += (l0 ? 0 : 1) + (l1 ? 0 : 1);
    }
    {
        float E = e[24];
        bool  l = E < egt;
        float q = (l ? E * inv : 0.f) + EPS_F;
        rc0 -= q * __logf(q);
        k   += l ? 0 : 1;
    }
    if (h == 0) {
        bool  l = e25 < egt;
        float q = (l ? e25 * inv : 0.f) + EPS_F;
        rc1 -= q * __logf(q);
        k   += l ? 0 : 1;
    }
    float rc = rc0 + rc1;
    float kf = (float)k;                         // <= 101, exact in float

    // Wave butterfly over the 3 per-lane scalars (sq nonzero only at h==0).
    #pragma unroll
    for (int off = 32; off >= 1; off >>= 1) {
        sq += __shfl_xor(sq, off);
        rc += __shfl_xor(rc, off);
        kf += __shfl_xor(kf, off);
    }
    if ((tid & 63) == 0) wsum[wv] = make_float4(sq, rc, kf, 0.f);
    __syncthreads();
    if (tid == 0) {
        float4 a = wsum[0], b = wsum[1], c = wsum[2], d = wsum[3];
        float ps = a.x + b.x + c.x + d.x;
        float pr = a.y + b.y + c.y + d.y;
        float pk = a.z + b.z + c.z + d.z;
        // Relaxed agent-scope stores: sc1 straight to the coherent point,
        // no L2 writeback. 12 B per block.
        float* pb = (float*)(partial + blockIdx.x);
        __hip_atomic_store(pb + 0, ps, __ATOMIC_RELAXED, __HIP_MEMORY_SCOPE_AGENT);
        __hip_atomic_store(pb + 1, pr, __ATOMIC_RELAXED, __HIP_MEMORY_SCOPE_AGENT);
        __hip_atomic_store(pb + 2, pk, __ATOMIC_RELAXED, __HIP_MEMORY_SCOPE_AGENT);
        // Own stores committed before the ticket RMW (manual release, no wbl2).
        asm volatile("s_waitcnt vmcnt(0)" ::: "memory");
        unsigned old = __hip_atomic_fetch_add(ticket, 1u, __ATOMIC_RELAXED,
                                              __HIP_MEMORY_SCOPE_AGENT);
        is_last = (old == NBLK - 1) ? 1 : 0;
    }
    __syncthreads();

    if (is_last) {
        // Ticket total order + per-writer vmcnt(0) => all partials are at the
        // coherent point; scoped loads bypass any locally cached lines.
        double s = 0.0, rr = 0.0, kk = 0.0;
        const float* pf = (const float*)partial;
        #pragma unroll
        for (int i = 0; i < NBLK / THREADS; ++i) {   // 32 strided reads/thread
            const float* pb = pf + (size_t)(tid + i * THREADS) * 4;
            float vx = __hip_atomic_load(pb + 0, __ATOMIC_RELAXED, __HIP_MEMORY_SCOPE_AGENT);
            float vy = __hip_atomic_load(pb + 1, __ATOMIC_RELAXED, __HIP_MEMORY_SCOPE_AGENT);
            float vz = __hip_atomic_load(pb + 2, __ATOMIC_RELAXED, __HIP_MEMORY_SCOPE_AGENT);
            s += (double)vx; rr += (double)vy; kk += (double)vz;
        }
        #pragma unroll
        for (int off = 32; off >= 1; off >>= 1) {
            s  += __shfl_xor(s, off);
            rr += __shfl_xor(rr, off);
            kk += __shfl_xor(kk, off);
        }
        __shared__ double sd[12];
        if ((tid & 63) == 0) { sd[wv * 3 + 0] = s; sd[wv * 3 + 1] = rr; sd[wv * 3 + 2] = kk; }
        __syncthreads();
        if (tid == 0) {
            double S = sd[0] + sd[3] + sd[6] + sd[9];
            double R = sd[1] + sd[4] + sd[7] + sd[10];
            double K = sd[2] + sd[5] + sd[8] + sd[11];
            const double n = (double)N_ROWS;
            out[0] = (float)(0.1  * (S / n));    // LAMBDA_1 * mean_loss (0.2 * 0.5)
            out[1] = (float)(0.05 * (R / n));    // LAMBDA_2 * residue_loss
            out[2] = (float)(K / n);             // batch_average_K
        }
    }
}

extern "C" void kernel_launch(void* const* d_in, const int* in_sizes, int n_in,
                              void* d_out, int out_size, void* d_ws, size_t ws_size,
                              hipStream_t stream) {
    const float* x   = (const float*)d_in[0];
    const int*   tgt = (const int*)d_in[1];
    float*    out     = (float*)d_out;
    float4*   partial = (float4*)d_ws;                    // 8192 * 16 B = 128 KiB
    unsigned* ticket  = (unsigned*)((char*)d_ws + NBLK * sizeof(float4));

    // Zero the ticket each iteration (kernel leaves it at 8192). Graph-safe.
    hipMemsetAsync(ticket, 0, sizeof(unsigned), stream);
    mrl_main<<<NBLK, THREADS, 0, stream>>>(x, tgt, partial, ticket, out);
}

// Round 9
// 292.299 us; speedup vs baseline: 2.2056x; 1.1219x over previous
//
#include <hip/hip_runtime.h>

#define N_ROWS   524288
#define W_BINS   101
#define EPS_F    1e-3f
#define RPB      64                    // rows per block (one 64x101 tile)
#define NBLK     (N_ROWS / RPB)        // 8192 blocks
#define TILE_F   (RPB * W_BINS)        // 6464 floats per tile (25,856 B LDS)
#define THREADS  256                   // 4 waves; each row split across a lane QUARTET

typedef const float __attribute__((address_space(1)))* gptr_t;
typedef float __attribute__((address_space(3)))* sptr_t;

// FINAL (revert to R2, best measured: 292.3 us, absmax 0).
// One block = one 64-row tile, FOUR waves. Flat DMA-to-LDS staging; each row
// computed by 4 lanes of one wave: row r = wv*16 + (tid&15), quarter h =
// (tid>>4)&3 owns cols {0..25, 26..50, 51..75, 76..100}; combine = shfl_xor
// 16/32. 25.9 KB LDS -> 6 blocks/CU, 24 waves/CU.
// Session ledger: intra-block DMA/compute split-phase = neutral (R4);
// single-kernel fusion via __threadfence = +352us (per-block L2 writeback, R6);
// fusion via relaxed agent-scope atomics = +35us (single-address RMW
// serialization across XCDs, R8). Two-kernel form is the measured optimum.
__global__ __launch_bounds__(THREADS) void mrl_main(const float* __restrict__ x,
                                                    const int* __restrict__ tgt,
                                                    float4* __restrict__ partial) {
    __shared__ float  sm[TILE_F];
    __shared__ float4 wsum[4];
    const int tid = threadIdx.x;                 // 0..255
    const int wv  = tid >> 6;                    // wave 0..3
    const float* gbase = x + (size_t)blockIdx.x * TILE_F;

    // Flat async DMA: 16 B/lane. Chunk q covers floats [q*1024, +1024);
    // wave w's sub-chunk [q*1024 + w*256, +256). LDS dest base is wave-uniform.
    #pragma unroll
    for (int q = 0; q < 6; ++q) {
        __builtin_amdgcn_global_load_lds((gptr_t)(gbase + q * 1024 + tid * 4),
                                         (sptr_t)(sm + q * 1024 + (wv << 8)), 16, 0, 0);
    }
    if (tid < 80) {                              // tail: floats 6144..6463
        __builtin_amdgcn_global_load_lds((gptr_t)(gbase + 6144 + tid * 4),
                                         (sptr_t)(sm + 6144 + (wv << 8)), 16, 0, 0);
    }

    const int r = (wv << 4) | (tid & 15);        // row 0..63 (16 rows per wave)
    const int h = (tid >> 4) & 3;                // which quarter of the row
    const int t = tgt[blockIdx.x * RPB + r];     // broadcast across the quartet

    __syncthreads();                             // drains vmcnt -> tile visible

    // h==0 owns 26 cols (0..25), h>0 own 25 each. Max index r*101+100 never
    // crosses a row. Banks: (5r + {0,26,51,76}) mod 32 spreads <=4-way.
    const int cb = (h == 0) ? 0 : (h * 25 + 1);  // {0,26,51,76}
    const float* rp = sm + r * W_BINS + cb;

    // Pass 1: e_i = exp(x_i) kept in registers; accumulate se, sum(e*a), e_gt.
    float e[25];
    float e25 = 0.f;
    float se0 = 0.f, se1 = 0.f, sa0 = 0.f, sa1 = 0.f, eg = 0.f;
    #pragma unroll
    for (int i = 0; i < 24; i += 2) {
        float E0 = __expf(rp[i]);
        float E1 = __expf(rp[i + 1]);
        e[i] = E0; e[i + 1] = E1;
        se0 += E0; sa0 += E0 * (float)(cb + i);
        se1 += E1; sa1 += E1 * (float)(cb + i + 1);
        eg = (cb + i     == t) ? E0 : eg;
        eg = (cb + i + 1 == t) ? E1 : eg;
    }
    {                                            // 25th owned col (i = 24)
        float E = __expf(rp[24]);
        e[24] = E;
        se0 += E; sa0 += E * (float)(cb + 24);
        eg = (cb + 24 == t) ? E : eg;
    }
    if (h == 0) {                                // 26th col of quarter 0 (col 25)
        e25 = __expf(rp[25]);
        se1 += e25; sa1 += e25 * 25.0f;
        eg = (t == 25) ? e25 : eg;
    }
    float se  = se0 + se1;
    float sea = sa0 + sa1;

    // Combine the 4 row-partners (tid bits 4,5 = h; same wave).
    se  += __shfl_xor(se, 16);  se  += __shfl_xor(se, 32);
    sea += __shfl_xor(sea, 16); sea += __shfl_xor(sea, 32);
    eg  += __shfl_xor(eg, 16);  eg  += __shfl_xor(eg, 32);
    const float egt = eg;                        // bit-exact e[t] (+0 from partners)
    const float inv = __builtin_amdgcn_rcpf(se);

    float sq = 0.f;
    if (h == 0) {                                // count mean-loss once per row
        float d = sea * inv - (float)t;
        sq = d * d;
    }

    // Pass 2: pure-register. e-space compare is scale-invariant; i==t -> not lt.
    float rc0 = 0.f, rc1 = 0.f;
    int   k   = 0;
    #pragma unroll
    for (int i = 0; i < 24; i += 2) {
        float E0 = e[i], E1 = e[i + 1];
        bool  l0 = E0 < egt, l1 = E1 < egt;
        float q0 = (l0 ? E0 * inv : 0.f) + EPS_F;
        float q1 = (l1 ? E1 * inv : 0.f) + EPS_F;
        rc0 -= q0 * __logf(q0);
        rc1 -= q1 * __logf(q1);
        k   += (l0 ? 0 : 1) + (l1 ? 0 : 1);
    }
    {
        float E = e[24];
        bool  l = E < egt;
        float q = (l ? E * inv : 0.f) + EPS_F;
        rc0 -= q * __logf(q);
        k   += l ? 0 : 1;
    }
    if (h == 0) {
        bool  l = e25 < egt;
        float q = (l ? e25 * inv : 0.f) + EPS_F;
        rc1 -= q * __logf(q);
        k   += l ? 0 : 1;
    }
    float rc = rc0 + rc1;
    float kf = (float)k;                         // <= 101, exact in float

    // Wave butterfly over the 3 per-lane scalars (sq nonzero only at h==0).
    #pragma unroll
    for (int off = 32; off >= 1; off >>= 1) {
        sq += __shfl_xor(sq, off);
        rc += __shfl_xor(rc, off);
        kf += __shfl_xor(kf, off);
    }
    if ((tid & 63) == 0) wsum[wv] = make_float4(sq, rc, kf, 0.f);
    __syncthreads();
    if (tid == 0) {
        float4 a = wsum[0], b = wsum[1], c = wsum[2], d = wsum[3];
        partial[blockIdx.x] = make_float4(a.x + b.x + c.x + d.x,
                                          a.y + b.y + c.y + d.y,
                                          a.z + b.z + c.z + d.z, 0.f);
    }
}

__global__ __launch_bounds__(1024) void mrl_reduce(const float4* __restrict__ partial,
                                                   float* __restrict__ out) {
    double s = 0.0, r = 0.0, k = 0.0;
    #pragma unroll
    for (int i = 0; i < 8; ++i) {                // 8192 = 1024 * 8
        float4 v = partial[threadIdx.x + (i << 10)];
        s += (double)v.x; r += (double)v.y; k += (double)v.z;
    }
    #pragma unroll
    for (int off = 32; off >= 1; off >>= 1) {
        s += __shfl_xor(s, off);
        r += __shfl_xor(r, off);
        k += __shfl_xor(k, off);
    }
    __shared__ double sd[48];
    const int w = threadIdx.x >> 6;              // 16 waves
    if ((threadIdx.x & 63) == 0) { sd[w * 3 + 0] = s; sd[w * 3 + 1] = r; sd[w * 3 + 2] = k; }
    __syncthreads();
    if (threadIdx.x == 0) {
        double S = 0.0, R = 0.0, K = 0.0;
        #pragma unroll
        for (int i = 0; i < 16; ++i) { S += sd[i * 3]; R += sd[i * 3 + 1]; K += sd[i * 3 + 2]; }
        const double n = (double)N_ROWS;
        out[0] = (float)(0.1  * (S / n));        // LAMBDA_1 * mean_loss (0.2 * 0.5)
        out[1] = (float)(0.05 * (R / n));        // LAMBDA_2 * residue_loss
        out[2] = (float)(K / n);                 // batch_average_K
    }
}

extern "C" void kernel_launch(void* const* d_in, const int* in_sizes, int n_in,
                              void* d_out, int out_size, void* d_ws, size_t ws_size,
                              hipStream_t stream) {
    const float* x   = (const float*)d_in[0];
    const int*   tgt = (const int*)d_in[1];
    float*  out     = (float*)d_out;
    float4* partial = (float4*)d_ws;    // 8192 * 16 B = 128 KiB, well under ws_size

    mrl_main<<<NBLK, THREADS, 0, stream>>>(x, tgt, partial);
    mrl_reduce<<<1, 1024, 0, stream>>>(partial, out);
}